// Round 4
// baseline (275.193 us; speedup 1.0000x reference)
//
#include <hip/hip_runtime.h>

typedef __attribute__((ext_vector_type(8))) short short8;
typedef __attribute__((ext_vector_type(4))) float f32x4;
typedef unsigned short u16;
typedef unsigned int u32;

// b=16, C=256, n=4096(64x64), HEADS=4, D=32, hidden=128, O3=384
// Inputs: fp32 (x, W_qkv, W_out, b_out). Output: fp32 (reference returns float32).

__device__ __forceinline__ u16 f2bf(float f) {
    u32 x = __float_as_uint(f);
    u32 r = (x + 0x7fffu + ((x >> 16) & 1u)) >> 16;
    return (u16)r;
}
__device__ __forceinline__ void bf4_to_f(u32 lo, u32 hi, float* out) {
    out[0] = __uint_as_float(lo << 16);
    out[1] = __uint_as_float(lo & 0xffff0000u);
    out[2] = __uint_as_float(hi << 16);
    out[3] = __uint_as_float(hi & 0xffff0000u);
}

// ---------------- K-1: convert W_qkv fp32 -> bf16 ----------------
__global__ __launch_bounds__(256) void k_convW(const float* __restrict__ W,
                                               u16* __restrict__ Wb) {
    int idx = blockIdx.x * 256 + threadIdx.x;   // 98304/4 = 24576 threads
    float4 v = *reinterpret_cast<const float4*>(W + idx * 4);
    u32 w0 = (u32)f2bf(v.x) | ((u32)f2bf(v.y) << 16);
    u32 w1 = (u32)f2bf(v.z) | ((u32)f2bf(v.w) << 16);
    uint2 o = {w0, w1};
    *reinterpret_cast<uint2*>(Wb + idx * 4) = o;
}

// ---------------- K0: transpose x[b][c][n] (fp32) -> xT[b][n][c] (bf16) ----------------
__global__ __launch_bounds__(256) void k_transpose(const float* __restrict__ x,
                                                   u16* __restrict__ xT) {
    __shared__ alignas(16) u16 tile[64 * 72];
    int t = threadIdx.x;
    int n0 = blockIdx.x * 64, c0 = blockIdx.y * 64, b = blockIdx.z;
    // read phase: fp32 -> bf16 into tile[c][n]
    int rr = t >> 4, nq = (t & 15) * 4;
#pragma unroll
    for (int i = 0; i < 4; i++) {
        int cl = i * 16 + rr;
        float4 v = *reinterpret_cast<const float4*>(x + ((size_t)(b * 256 + c0 + cl) * 4096 + n0 + nq));
        u32 w0 = (u32)f2bf(v.x) | ((u32)f2bf(v.y) << 16);
        u32 w1 = (u32)f2bf(v.z) | ((u32)f2bf(v.w) << 16);
        uint2 o = {w0, w1};
        *reinterpret_cast<uint2*>(&tile[cl * 72 + nq]) = o;
    }
    __syncthreads();
    // write phase: xT[n][c]
    int r = t >> 3, c8 = (t & 7) * 8;
#pragma unroll
    for (int i = 0; i < 2; i++) {
        int nl = i * 32 + r;
        alignas(16) u16 vals[8];
#pragma unroll
        for (int j = 0; j < 8; j++) vals[j] = tile[(c8 + j) * 72 + nl];
        *reinterpret_cast<uint4*>(xT + ((size_t)(b * 4096 + n0 + nl) * 256 + c0 + c8)) =
            *reinterpret_cast<const uint4*>(vals);
    }
}

// ---------------- K1: qkv GEMM (fused dual-layout epilogue) ----------------
// qT[b][n][e]   (e<128, q stored transposed)  D' = xT(16n x 32c) * W^T(32c x 16e)
// kbuf[b][o][n] (o = row-128)                 D  = W (16o x 32c) * xB(32c x 16n)
// vbuf[b][o][n] (o = row-256)
__global__ __launch_bounds__(256) void k_qkv(const u16* __restrict__ xT,
                                             const u16* __restrict__ W,
                                             u16* __restrict__ qT,
                                             u16* __restrict__ kbuf,
                                             u16* __restrict__ vbuf) {
    __shared__ alignas(16) u16 sW[384 * 72];
    __shared__ alignas(16) u16 sX[64 * 72];
    int t = threadIdx.x;
    int n0 = blockIdx.x * 64, b = blockIdx.y;
    int lane = t & 63, wv = t >> 6, l16 = lane & 15, lq = lane >> 4;
    int r = t >> 3, c8 = (t & 7) * 8;

    f32x4 acc[6][4];
#pragma unroll
    for (int i = 0; i < 6; i++)
#pragma unroll
        for (int j = 0; j < 4; j++) acc[i][j] = (f32x4){0.f, 0.f, 0.f, 0.f};

    for (int kc = 0; kc < 4; kc++) {
        __syncthreads();
#pragma unroll
        for (int i = 0; i < 12; i++) {
            int o = i * 32 + r;
            *reinterpret_cast<uint4*>(&sW[o * 72 + c8]) =
                *reinterpret_cast<const uint4*>(W + o * 256 + kc * 64 + c8);
        }
#pragma unroll
        for (int i = 0; i < 2; i++) {
            int nl = i * 32 + r;
            *reinterpret_cast<uint4*>(&sX[nl * 72 + c8]) =
                *reinterpret_cast<const uint4*>(xT + (size_t)(b * 4096 + n0 + nl) * 256 + kc * 64 + c8);
        }
        __syncthreads();
#pragma unroll
        for (int ks = 0; ks < 2; ks++) {
            int col = ks * 32 + lq * 8;
            short8 wf[6], xf[4];
#pragma unroll
            for (int i = 0; i < 6; i++) {
                int row = (wv * 6 + i) * 16 + l16;
                wf[i] = *reinterpret_cast<const short8*>(&sW[row * 72 + col]);
            }
#pragma unroll
            for (int j = 0; j < 4; j++) {
                int row = j * 16 + l16;
                xf[j] = *reinterpret_cast<const short8*>(&sX[row * 72 + col]);
            }
#pragma unroll
            for (int i = 0; i < 6; i++) {
                bool isq = ((wv * 6 + i) * 16) < 128;
#pragma unroll
                for (int j = 0; j < 4; j++) {
                    if (isq)
                        acc[i][j] = __builtin_amdgcn_mfma_f32_16x16x32_bf16(xf[j], wf[i], acc[i][j], 0, 0, 0);
                    else
                        acc[i][j] = __builtin_amdgcn_mfma_f32_16x16x32_bf16(wf[i], xf[j], acc[i][j], 0, 0, 0);
                }
            }
        }
    }
    // epilogue (C/D layout: col=lane&15, row=lq*4+reg — m89/m91; R2==R3 confirmed both paths)
#pragma unroll
    for (int i = 0; i < 6; i++) {
        int obase = (wv * 6 + i) * 16;
#pragma unroll
        for (int j = 0; j < 4; j++) {
            int nbase = n0 + j * 16;
            f32x4 a = acc[i][j];
            if (obase < 128) {
                int e = obase + l16;
#pragma unroll
                for (int rr = 0; rr < 4; rr++) {
                    int n = nbase + lq * 4 + rr;
                    qT[(size_t)(b * 4096 + n) * 128 + e] = f2bf(a[rr]);
                }
            } else {
                int n = nbase + l16;
                u16* dst = (obase < 256) ? kbuf : vbuf;
                int rb = (obase < 256) ? (obase - 128) : (obase - 256);
#pragma unroll
                for (int rr = 0; rr < 4; rr++) {
                    int o = rb + lq * 4 + rr;
                    dst[(size_t)(b * 128 + o) * 4096 + n] = f2bf(a[rr]);
                }
            }
        }
    }
}

// ---------------- K2: per-row softmax of k (in-place, bf16) ----------------
__global__ __launch_bounds__(256) void k_softmax(const u16* __restrict__ kbuf,
                                                 u16* __restrict__ pbuf) {
    __shared__ float red[4];
    __shared__ float red2[4];
    int bi = blockIdx.x;
    int b = bi >> 7, hd = bi & 127;
    const u16* row = kbuf + (size_t)(b * 128 + hd) * 4096;
    u16* prow = pbuf + (size_t)(b * 128 + hd) * 4096;
    int t = threadIdx.x;
    float f[16];
#pragma unroll
    for (int i = 0; i < 2; i++) {
        uint4 v = *reinterpret_cast<const uint4*>(row + (t + i * 256) * 8);
        u32 w[4] = {v.x, v.y, v.z, v.w};
#pragma unroll
        for (int j = 0; j < 4; j++) {
            f[i * 8 + j * 2 + 0] = __uint_as_float(w[j] << 16);
            f[i * 8 + j * 2 + 1] = __uint_as_float(w[j] & 0xffff0000u);
        }
    }
    float mx = f[0];
#pragma unroll
    for (int i = 1; i < 16; i++) mx = fmaxf(mx, f[i]);
#pragma unroll
    for (int off = 32; off > 0; off >>= 1) mx = fmaxf(mx, __shfl_down(mx, off, 64));
    int wv = t >> 6;
    if ((t & 63) == 0) red[wv] = mx;
    __syncthreads();
    mx = fmaxf(fmaxf(red[0], red[1]), fmaxf(red[2], red[3]));
    float s = 0.f;
#pragma unroll
    for (int i = 0; i < 16; i++) { f[i] = __expf(f[i] - mx); s += f[i]; }
#pragma unroll
    for (int off = 32; off > 0; off >>= 1) s += __shfl_down(s, off, 64);
    if ((t & 63) == 0) red2[wv] = s;
    __syncthreads();
    s = red2[0] + red2[1] + red2[2] + red2[3];
    float inv = 1.0f / s;
#pragma unroll
    for (int i = 0; i < 2; i++) {
        u32 w[4];
#pragma unroll
        for (int j = 0; j < 4; j++) {
            u32 lo = f2bf(f[i * 8 + j * 2 + 0] * inv);
            u32 hi = f2bf(f[i * 8 + j * 2 + 1] * inv);
            w[j] = lo | (hi << 16);
        }
        uint4 v = {w[0], w[1], w[2], w[3]};
        *reinterpret_cast<uint4*>(prow + (t + i * 256) * 8) = v;
    }
}

// ---------------- K3: context partials: ctx[d][e] += P[d][n]*V[e][n] ----------------
__global__ __launch_bounds__(256) void k_ctx(const u16* __restrict__ pbuf,
                                             const u16* __restrict__ vbuf,
                                             float* __restrict__ part) {
    int s = blockIdx.x, h = blockIdx.y, b = blockIdx.z;
    int t = threadIdx.x;
    int g = t >> 6, t64 = t & 63;
    int d0 = (t64 >> 3) * 4, e0 = (t64 & 7) * 4;
    int n0 = s * 512 + g * 128;
    const u16* Pb = pbuf + (size_t)(b * 128 + h * 32) * 4096;
    const u16* Vb = vbuf + (size_t)(b * 128 + h * 32) * 4096;
    float acc[4][4] = {};
    for (int nn = 0; nn < 128; nn += 4) {
        int n = n0 + nn;
        float pf[4][4], vf[4][4];
#pragma unroll
        for (int i = 0; i < 4; i++) {
            uint2 up = *reinterpret_cast<const uint2*>(Pb + (d0 + i) * 4096 + n);
            bf4_to_f(up.x, up.y, pf[i]);
            uint2 uv = *reinterpret_cast<const uint2*>(Vb + (e0 + i) * 4096 + n);
            bf4_to_f(uv.x, uv.y, vf[i]);
        }
#pragma unroll
        for (int i = 0; i < 4; i++)
#pragma unroll
            for (int j = 0; j < 4; j++)
#pragma unroll
                for (int kk = 0; kk < 4; kk++)
                    acc[i][j] += pf[i][kk] * vf[j][kk];
    }
    int bh = b * 4 + h;
    float* dst = part + (size_t)(bh * 32 + s * 4 + g) * 1024;
#pragma unroll
    for (int i = 0; i < 4; i++)
#pragma unroll
        for (int j = 0; j < 4; j++)
            dst[(d0 + i) * 32 + e0 + j] = acc[i][j];
}

// ---------------- K4: reduce partials ----------------
__global__ __launch_bounds__(256) void k_ctxred(const float* __restrict__ part,
                                                float* __restrict__ ctx) {
    int bh = blockIdx.x;
    int t = threadIdx.x;
#pragma unroll
    for (int r = 0; r < 4; r++) {
        int de = t + r * 256;
        float s = 0.f;
        for (int p = 0; p < 32; p++) s += part[(size_t)(bh * 32 + p) * 1024 + de];
        ctx[(size_t)bh * 1024 + de] = s;
    }
}

// ---------------- K5: M[b][o][h*32+e] = sum_d Wout[o][h*32+d] * ctx[b][h][d][e] ----------------
__global__ __launch_bounds__(256) void k_M(const float* __restrict__ ctx,
                                           const float* __restrict__ Wout,
                                           u16* __restrict__ Mb) {
    __shared__ float sc[4096];
    int b = blockIdx.x, t = threadIdx.x;
#pragma unroll
    for (int i = 0; i < 16; i++) sc[t + i * 256] = ctx[b * 4096 + t + i * 256];
    __syncthreads();
    int o = t;
#pragma unroll
    for (int h = 0; h < 4; h++) {
        float wv[32];
#pragma unroll
        for (int d = 0; d < 32; d++) wv[d] = Wout[o * 128 + h * 32 + d];
        for (int e = 0; e < 32; e++) {
            float a = 0.f;
#pragma unroll
            for (int d = 0; d < 32; d++) a += wv[d] * sc[(h * 32 + d) * 32 + e];
            Mb[(b * 256 + o) * 128 + h * 32 + e] = f2bf(a);
        }
    }
}

// ---------------- K6: y[b][o][n] = sum_e M[b][o][e] * qT[b][n][e] + bias[o]  (fp32 out) ----------------
__global__ __launch_bounds__(256) void k_y(const u16* __restrict__ Mb,
                                           const u16* __restrict__ qT,
                                           const float* __restrict__ bout,
                                           float* __restrict__ y) {
    __shared__ alignas(16) u16 sM[256 * 72];
    __shared__ alignas(16) u16 sQ[64 * 72];
    int t = threadIdx.x;
    int n0 = blockIdx.x * 64, b = blockIdx.y;
    int lane = t & 63, wv = t >> 6, l16 = lane & 15, lq = lane >> 4;
    int r = t >> 3, c8 = (t & 7) * 8;
    f32x4 acc[4][4];
#pragma unroll
    for (int i = 0; i < 4; i++)
#pragma unroll
        for (int j = 0; j < 4; j++) acc[i][j] = (f32x4){0.f, 0.f, 0.f, 0.f};

    for (int kc = 0; kc < 2; kc++) {
        __syncthreads();
#pragma unroll
        for (int i = 0; i < 8; i++) {
            int o = i * 32 + r;
            *reinterpret_cast<uint4*>(&sM[o * 72 + c8]) =
                *reinterpret_cast<const uint4*>(Mb + (b * 256 + o) * 128 + kc * 64 + c8);
        }
#pragma unroll
        for (int i = 0; i < 2; i++) {
            int nl = i * 32 + r;
            *reinterpret_cast<uint4*>(&sQ[nl * 72 + c8]) =
                *reinterpret_cast<const uint4*>(qT + (size_t)(b * 4096 + n0 + nl) * 128 + kc * 64 + c8);
        }
        __syncthreads();
#pragma unroll
        for (int ks = 0; ks < 2; ks++) {
            int col = ks * 32 + lq * 8;
            short8 mf[4], qf[4];
#pragma unroll
            for (int i = 0; i < 4; i++)
                mf[i] = *reinterpret_cast<const short8*>(&sM[((wv * 4 + i) * 16 + l16) * 72 + col]);
#pragma unroll
            for (int j = 0; j < 4; j++)
                qf[j] = *reinterpret_cast<const short8*>(&sQ[(j * 16 + l16) * 72 + col]);
#pragma unroll
            for (int i = 0; i < 4; i++)
#pragma unroll
                for (int j = 0; j < 4; j++)
                    acc[i][j] = __builtin_amdgcn_mfma_f32_16x16x32_bf16(mf[i], qf[j], acc[i][j], 0, 0, 0);
        }
    }
#pragma unroll
    for (int i = 0; i < 4; i++) {
        int obase = (wv * 4 + i) * 16;
#pragma unroll
        for (int j = 0; j < 4; j++) {
            int n = n0 + j * 16 + l16;
#pragma unroll
            for (int rr = 0; rr < 4; rr++) {
                int o = obase + lq * 4 + rr;
                float val = acc[i][j][rr] + bout[o];
                y[((size_t)(b * 256 + o)) * 4096 + n] = val;
            }
        }
    }
}

extern "C" void kernel_launch(void* const* d_in, const int* in_sizes, int n_in,
                              void* d_out, int out_size, void* d_ws, size_t ws_size,
                              hipStream_t stream) {
    const float* x    = (const float*)d_in[0];
    const float* Wqkv = (const float*)d_in[1];
    const float* Wout = (const float*)d_in[2];
    const float* bout = (const float*)d_in[3];
    float* y = (float*)d_out;

    // xT (bf16, 32 MB) borrows the front of d_out (fp32, 64 MB); dead after k_qkv,
    // fully overwritten by k_y at the end.
    u16* xT = (u16*)d_out;

    char* ws = (char*)d_ws;
    u16*   qT   = (u16*)(ws);                     // 16 MB
    u16*   kb   = (u16*)(ws + 16777216);          // 16 MB (softmax in-place -> P)
    u16*   vb   = (u16*)(ws + 33554432);          // 16 MB
    float* part = (float*)(ws + 50331648);        // 8 MB
    float* ctx  = (float*)(ws + 58720256);        // 256 KB
    u16*   Mb   = (u16*)(ws + 58982400);          // 1 MB
    u16*   Wb   = (u16*)(ws + 60030976);          // 192 KB

    k_convW<<<96, 256, 0, stream>>>(Wqkv, Wb);
    k_transpose<<<dim3(64, 4, 16), 256, 0, stream>>>(x, xT);
    k_qkv<<<dim3(64, 16), 256, 0, stream>>>(xT, Wb, qT, kb, vb);
    k_softmax<<<2048, 256, 0, stream>>>(kb, kb);
    k_ctx<<<dim3(8, 4, 16), 256, 0, stream>>>(kb, vb, part);
    k_ctxred<<<64, 256, 0, stream>>>(part, ctx);
    k_M<<<16, 256, 0, stream>>>(ctx, Wout, Mb);
    k_y<<<dim3(64, 16), 256, 0, stream>>>(Mb, qT, bout, y);
}

// Round 5
// 214.293 us; speedup vs baseline: 1.2842x; 1.2842x over previous
//
#include <hip/hip_runtime.h>

typedef __attribute__((ext_vector_type(8))) short short8;
typedef __attribute__((ext_vector_type(4))) float f32x4;
typedef unsigned short u16;
typedef unsigned int u32;

// b=16, C=256, n=4096(64x64), HEADS=4, D=32, hidden=128, O3=384
// Inputs fp32, output fp32. Internal compute bf16 MFMA.

__device__ __forceinline__ u16 f2bf(float f) {
    u32 x = __float_as_uint(f);
    u32 r = (x + 0x7fffu + ((x >> 16) & 1u)) >> 16;
    return (u16)r;
}

// ---------------- K-1: convert W_qkv fp32 -> bf16 ----------------
__global__ __launch_bounds__(256) void k_convW(const float* __restrict__ W,
                                               u16* __restrict__ Wb) {
    int idx = blockIdx.x * 256 + threadIdx.x;   // 98304/4 = 24576 threads
    float4 v = *reinterpret_cast<const float4*>(W + idx * 4);
    u32 w0 = (u32)f2bf(v.x) | ((u32)f2bf(v.y) << 16);
    u32 w1 = (u32)f2bf(v.z) | ((u32)f2bf(v.w) << 16);
    uint2 o = {w0, w1};
    *reinterpret_cast<uint2*>(Wb + idx * 4) = o;
}

// ---------------- K0: transpose x[b][c][n] (fp32) -> xT[b][n][c] (bf16) ----------------
__global__ __launch_bounds__(256) void k_transpose(const float* __restrict__ x,
                                                   u16* __restrict__ xT) {
    __shared__ alignas(16) u16 tile[64 * 72];
    int t = threadIdx.x;
    int n0 = blockIdx.x * 64, c0 = blockIdx.y * 64, b = blockIdx.z;
    int rr = t >> 4, nq = (t & 15) * 4;
#pragma unroll
    for (int i = 0; i < 4; i++) {
        int cl = i * 16 + rr;
        float4 v = *reinterpret_cast<const float4*>(x + ((size_t)(b * 256 + c0 + cl) * 4096 + n0 + nq));
        u32 w0 = (u32)f2bf(v.x) | ((u32)f2bf(v.y) << 16);
        u32 w1 = (u32)f2bf(v.z) | ((u32)f2bf(v.w) << 16);
        uint2 o = {w0, w1};
        *reinterpret_cast<uint2*>(&tile[cl * 72 + nq]) = o;
    }
    __syncthreads();
    int r = t >> 3, c8 = (t & 7) * 8;
#pragma unroll
    for (int i = 0; i < 2; i++) {
        int nl = i * 32 + r;
        alignas(16) u16 vals[8];
#pragma unroll
        for (int j = 0; j < 8; j++) vals[j] = tile[(c8 + j) * 72 + nl];
        *reinterpret_cast<uint4*>(xT + ((size_t)(b * 4096 + n0 + nl) * 256 + c0 + c8)) =
            *reinterpret_cast<const uint4*>(vals);
    }
}

// ---------------- K1: qkv GEMM, 128x128 tile ----------------
// grid (mt=3, nt=32, b=16); mt innermost so consecutive blocks share the xT tile in L2.
// mt=0 -> qT[b][n][e] (packed 4-bf16 stores), mt=1 -> kbuf[b][o][n], mt=2 -> vbuf
__global__ __launch_bounds__(256) void k_qkv(const u16* __restrict__ xT,
                                             const u16* __restrict__ W,
                                             u16* __restrict__ qT,
                                             u16* __restrict__ kbuf,
                                             u16* __restrict__ vbuf) {
    __shared__ alignas(16) u16 sA[128 * 72];
    __shared__ alignas(16) u16 sB[128 * 72];
    int t = threadIdx.x;
    int mt = blockIdx.x, n0 = blockIdx.y * 128, b = blockIdx.z;
    int m0 = mt * 128;
    int lane = t & 63, wv = t >> 6, l16 = lane & 15, lq = lane >> 4;
    int wr = wv >> 1, wc = wv & 1;
    int r = t >> 3, c8 = (t & 7) * 8;

    f32x4 acc[4][4];
#pragma unroll
    for (int i = 0; i < 4; i++)
#pragma unroll
        for (int j = 0; j < 4; j++) acc[i][j] = (f32x4){0.f, 0.f, 0.f, 0.f};

    for (int kc = 0; kc < 4; kc++) {
        __syncthreads();
#pragma unroll
        for (int i = 0; i < 4; i++) {
            int row = i * 32 + r;
            *reinterpret_cast<uint4*>(&sA[row * 72 + c8]) =
                *reinterpret_cast<const uint4*>(W + (m0 + row) * 256 + kc * 64 + c8);
            *reinterpret_cast<uint4*>(&sB[row * 72 + c8]) =
                *reinterpret_cast<const uint4*>(xT + (size_t)(b * 4096 + n0 + row) * 256 + kc * 64 + c8);
        }
        __syncthreads();
#pragma unroll
        for (int ks = 0; ks < 2; ks++) {
            int col = ks * 32 + lq * 8;
            short8 af[4], bf[4];
#pragma unroll
            for (int i = 0; i < 4; i++)
                af[i] = *reinterpret_cast<const short8*>(&sA[(wr * 64 + i * 16 + l16) * 72 + col]);
#pragma unroll
            for (int j = 0; j < 4; j++)
                bf[j] = *reinterpret_cast<const short8*>(&sB[(wc * 64 + j * 16 + l16) * 72 + col]);
#pragma unroll
            for (int i = 0; i < 4; i++)
#pragma unroll
                for (int j = 0; j < 4; j++)
                    acc[i][j] = __builtin_amdgcn_mfma_f32_16x16x32_bf16(af[i], bf[j], acc[i][j], 0, 0, 0);
        }
    }
    // epilogue: D[o][n] with row=lq*4+rr, col=l16 (m89/m91-verified)
    if (mt == 0) {
        // q: o is the e dim; write qT[b][n][e] packing 4 consecutive e per lane
#pragma unroll
        for (int i = 0; i < 4; i++) {
            int ebase = wr * 64 + i * 16 + lq * 4;
#pragma unroll
            for (int j = 0; j < 4; j++) {
                int n = n0 + wc * 64 + j * 16 + l16;
                f32x4 a = acc[i][j];
                u32 w0 = (u32)f2bf(a[0]) | ((u32)f2bf(a[1]) << 16);
                u32 w1 = (u32)f2bf(a[2]) | ((u32)f2bf(a[3]) << 16);
                uint2 o = {w0, w1};
                *reinterpret_cast<uint2*>(qT + (size_t)(b * 4096 + n) * 128 + ebase) = o;
            }
        }
    } else {
        u16* dst = (mt == 1) ? kbuf : vbuf;
#pragma unroll
        for (int i = 0; i < 4; i++) {
            int obase = wr * 64 + i * 16 + lq * 4;
#pragma unroll
            for (int j = 0; j < 4; j++) {
                int n = n0 + wc * 64 + j * 16 + l16;
                f32x4 a = acc[i][j];
#pragma unroll
                for (int rr = 0; rr < 4; rr++)
                    dst[(size_t)(b * 128 + obase + rr) * 4096 + n] = f2bf(a[rr]);
            }
        }
    }
}

// ---------------- K2: per-row softmax of k (in-place, bf16) ----------------
__global__ __launch_bounds__(256) void k_softmax(const u16* __restrict__ kbuf,
                                                 u16* __restrict__ pbuf) {
    __shared__ float red[4];
    __shared__ float red2[4];
    int bi = blockIdx.x;
    int b = bi >> 7, hd = bi & 127;
    const u16* row = kbuf + (size_t)(b * 128 + hd) * 4096;
    u16* prow = pbuf + (size_t)(b * 128 + hd) * 4096;
    int t = threadIdx.x;
    float f[16];
#pragma unroll
    for (int i = 0; i < 2; i++) {
        uint4 v = *reinterpret_cast<const uint4*>(row + (t + i * 256) * 8);
        u32 w[4] = {v.x, v.y, v.z, v.w};
#pragma unroll
        for (int j = 0; j < 4; j++) {
            f[i * 8 + j * 2 + 0] = __uint_as_float(w[j] << 16);
            f[i * 8 + j * 2 + 1] = __uint_as_float(w[j] & 0xffff0000u);
        }
    }
    float mx = f[0];
#pragma unroll
    for (int i = 1; i < 16; i++) mx = fmaxf(mx, f[i]);
#pragma unroll
    for (int off = 32; off > 0; off >>= 1) mx = fmaxf(mx, __shfl_down(mx, off, 64));
    int wv = t >> 6;
    if ((t & 63) == 0) red[wv] = mx;
    __syncthreads();
    mx = fmaxf(fmaxf(red[0], red[1]), fmaxf(red[2], red[3]));
    float s = 0.f;
#pragma unroll
    for (int i = 0; i < 16; i++) { f[i] = __expf(f[i] - mx); s += f[i]; }
#pragma unroll
    for (int off = 32; off > 0; off >>= 1) s += __shfl_down(s, off, 64);
    if ((t & 63) == 0) red2[wv] = s;
    __syncthreads();
    s = red2[0] + red2[1] + red2[2] + red2[3];
    float inv = 1.0f / s;
#pragma unroll
    for (int i = 0; i < 2; i++) {
        u32 w[4];
#pragma unroll
        for (int j = 0; j < 4; j++) {
            u32 lo = f2bf(f[i * 8 + j * 2 + 0] * inv);
            u32 hi = f2bf(f[i * 8 + j * 2 + 1] * inv);
            w[j] = lo | (hi << 16);
        }
        uint4 v = {w[0], w[1], w[2], w[3]};
        *reinterpret_cast<uint4*>(prow + (t + i * 256) * 8) = v;
    }
}

// ---------------- K3: context via MFMA: part[bh][s][d][e] = P(32xN) * V(32xN)^T ----------------
// grid (s=8, h=4, b=16); 4 waves split n (128 each of the 512-slice); fragments direct from global.
__global__ __launch_bounds__(256) void k_ctx(const u16* __restrict__ pbuf,
                                             const u16* __restrict__ vbuf,
                                             float* __restrict__ part) {
    __shared__ float sred[4][32][32];
    int s = blockIdx.x, h = blockIdx.y, b = blockIdx.z;
    int t = threadIdx.x;
    int lane = t & 63, wv = t >> 6, l16 = lane & 15, lq = lane >> 4;
    const u16* Pb = pbuf + (size_t)(b * 128 + h * 32) * 4096;
    const u16* Vb = vbuf + (size_t)(b * 128 + h * 32) * 4096;
    int nb = s * 512 + wv * 128;

    f32x4 acc[2][2];
#pragma unroll
    for (int i = 0; i < 2; i++)
#pragma unroll
        for (int j = 0; j < 2; j++) acc[i][j] = (f32x4){0.f, 0.f, 0.f, 0.f};

#pragma unroll
    for (int kk = 0; kk < 4; kk++) {
        int col = nb + kk * 32 + lq * 8;
        short8 af[2], bf[2];
#pragma unroll
        for (int i = 0; i < 2; i++)
            af[i] = *reinterpret_cast<const short8*>(Pb + (size_t)(i * 16 + l16) * 4096 + col);
#pragma unroll
        for (int j = 0; j < 2; j++)
            bf[j] = *reinterpret_cast<const short8*>(Vb + (size_t)(j * 16 + l16) * 4096 + col);
#pragma unroll
        for (int i = 0; i < 2; i++)
#pragma unroll
            for (int j = 0; j < 2; j++)
                acc[i][j] = __builtin_amdgcn_mfma_f32_16x16x32_bf16(af[i], bf[j], acc[i][j], 0, 0, 0);
    }
    // D[d][e]: row=lq*4+rr -> d, col=l16 -> e
#pragma unroll
    for (int i = 0; i < 2; i++)
#pragma unroll
        for (int j = 0; j < 2; j++)
#pragma unroll
            for (int rr = 0; rr < 4; rr++)
                sred[wv][i * 16 + lq * 4 + rr][j * 16 + l16] = acc[i][j][rr];
    __syncthreads();
    // reduce 4 waves -> part
    int de0 = t * 4;
    const float* s0 = &sred[0][0][0];
    f32x4 sum;
#pragma unroll
    for (int q = 0; q < 4; q++)
        sum[q] = s0[de0 + q] + s0[1024 + de0 + q] + s0[2048 + de0 + q] + s0[3072 + de0 + q];
    int bh = b * 4 + h;
    *reinterpret_cast<f32x4*>(part + (size_t)(bh * 8 + s) * 1024 + de0) = sum;
}

// ---------------- K4: reduce partials + M = Wout x ctx_blockdiag -> Mb bf16 ----------------
// grid (b=16); sc[h*1024 + d*32 + e] = ctx
__global__ __launch_bounds__(256) void k_Mred(const float* __restrict__ part,
                                              const float* __restrict__ Wout,
                                              u16* __restrict__ Mb) {
    __shared__ float sc[4096];
    int b = blockIdx.x, t = threadIdx.x;
#pragma unroll
    for (int it = 0; it < 16; it++) {
        int idx = it * 256 + t;          // h*1024 + de
        int h = idx >> 10, de = idx & 1023;
        float s = 0.f;
#pragma unroll
        for (int p = 0; p < 8; p++) s += part[(size_t)((b * 4 + h) * 8 + p) * 1024 + de];
        sc[idx] = s;
    }
    __syncthreads();
    int o = t;
#pragma unroll
    for (int h = 0; h < 4; h++) {
        float wvv[32];
#pragma unroll
        for (int d = 0; d < 32; d++) wvv[d] = Wout[o * 128 + h * 32 + d];
        for (int e = 0; e < 32; e++) {
            float a = 0.f;
#pragma unroll
            for (int d = 0; d < 32; d++) a += wvv[d] * sc[h * 1024 + d * 32 + e];
            Mb[(b * 256 + o) * 128 + h * 32 + e] = f2bf(a);
        }
    }
}

// ---------------- K5: y = M x qT^T + bias, 128x128 tile, fp32 out ----------------
// grid (mt=2, nt=32, b=16)
__global__ __launch_bounds__(256) void k_y(const u16* __restrict__ Mb,
                                           const u16* __restrict__ qT,
                                           const float* __restrict__ bout,
                                           float* __restrict__ y) {
    __shared__ alignas(16) u16 sA[128 * 72];
    __shared__ alignas(16) u16 sB[128 * 72];
    int t = threadIdx.x;
    int mt = blockIdx.x, n0 = blockIdx.y * 128, b = blockIdx.z;
    int m0 = mt * 128;
    int lane = t & 63, wv = t >> 6, l16 = lane & 15, lq = lane >> 4;
    int wr = wv >> 1, wc = wv & 1;
    int r = t >> 3, c8 = (t & 7) * 8;

    f32x4 acc[4][4];
#pragma unroll
    for (int i = 0; i < 4; i++)
#pragma unroll
        for (int j = 0; j < 4; j++) acc[i][j] = (f32x4){0.f, 0.f, 0.f, 0.f};

    for (int kc = 0; kc < 2; kc++) {
        __syncthreads();
#pragma unroll
        for (int i = 0; i < 4; i++) {
            int row = i * 32 + r;
            *reinterpret_cast<uint4*>(&sA[row * 72 + c8]) =
                *reinterpret_cast<const uint4*>(Mb + (b * 256 + m0 + row) * 128 + kc * 64 + c8);
            *reinterpret_cast<uint4*>(&sB[row * 72 + c8]) =
                *reinterpret_cast<const uint4*>(qT + (size_t)(b * 4096 + n0 + row) * 128 + kc * 64 + c8);
        }
        __syncthreads();
#pragma unroll
        for (int ks = 0; ks < 2; ks++) {
            int col = ks * 32 + lq * 8;
            short8 af[4], bf[4];
#pragma unroll
            for (int i = 0; i < 4; i++)
                af[i] = *reinterpret_cast<const short8*>(&sA[(wr * 64 + i * 16 + l16) * 72 + col]);
#pragma unroll
            for (int j = 0; j < 4; j++)
                bf[j] = *reinterpret_cast<const short8*>(&sB[(wc * 64 + j * 16 + l16) * 72 + col]);
#pragma unroll
            for (int i = 0; i < 4; i++)
#pragma unroll
                for (int j = 0; j < 4; j++)
                    acc[i][j] = __builtin_amdgcn_mfma_f32_16x16x32_bf16(af[i], bf[j], acc[i][j], 0, 0, 0);
        }
    }
#pragma unroll
    for (int i = 0; i < 4; i++) {
        int obase = m0 + wr * 64 + i * 16 + lq * 4;
#pragma unroll
        for (int j = 0; j < 4; j++) {
            int n = n0 + wc * 64 + j * 16 + l16;
#pragma unroll
            for (int rr = 0; rr < 4; rr++) {
                int o = obase + rr;
                y[(size_t)(b * 256 + o) * 4096 + n] = acc[i][j][rr] + bout[o];
            }
        }
    }
}

extern "C" void kernel_launch(void* const* d_in, const int* in_sizes, int n_in,
                              void* d_out, int out_size, void* d_ws, size_t ws_size,
                              hipStream_t stream) {
    const float* x    = (const float*)d_in[0];
    const float* Wqkv = (const float*)d_in[1];
    const float* Wout = (const float*)d_in[2];
    const float* bout = (const float*)d_in[3];
    float* y = (float*)d_out;

    // xT (bf16, 32 MB) borrows the front of d_out (fp32, 64 MB); dead after k_qkv.
    u16* xT = (u16*)d_out;

    char* ws = (char*)d_ws;
    u16*   qT   = (u16*)(ws);                     // 16 MB
    u16*   kb   = (u16*)(ws + 16777216);          // 16 MB (softmax in-place -> P)
    u16*   vb   = (u16*)(ws + 33554432);          // 16 MB
    float* part = (float*)(ws + 50331648);        // 2 MB
    u16*   Mb   = (u16*)(ws + 52428800);          // 1 MB
    u16*   Wb   = (u16*)(ws + 53477376);          // 192 KB

    k_convW<<<96, 256, 0, stream>>>(Wqkv, Wb);
    k_transpose<<<dim3(64, 4, 16), 256, 0, stream>>>(x, xT);
    k_qkv<<<dim3(3, 32, 16), 256, 0, stream>>>(xT, Wb, qT, kb, vb);
    k_softmax<<<2048, 256, 0, stream>>>(kb, kb);
    k_ctx<<<dim3(8, 4, 16), 256, 0, stream>>>(kb, vb, part);
    k_Mred<<<16, 256, 0, stream>>>(part, Wout, Mb);
    k_y<<<dim3(2, 32, 16), 256, 0, stream>>>(Mb, qT, bout, y);
}